// Round 5
// baseline (164.671 us; speedup 1.0000x reference)
//
#include <hip/hip_runtime.h>
#include <hip/hip_bf16.h>
#include <stdint.h>

#define N_SPK 2048
#define UU 32
#define DD 256
#define HALF_U 16
#define M_ROWS (N_SPK * HALF_U)   // 32768 test rows

#define BM 256
#define BN 128
#define BK 64
#define NSTEP 32                  // 8 tiles (bn) x 4 kt, one chained pipeline

typedef __attribute__((ext_vector_type(8))) short short8;   // 8 bf16 = 4 VGPRs
typedef __attribute__((ext_vector_type(4))) float f32x4;

typedef const __attribute__((address_space(1))) void ga_void;
typedef __attribute__((address_space(3))) void ls_void;

__device__ __forceinline__ void gld16(const void* g, void* l) {
    __builtin_amdgcn_global_load_lds((ga_void*)(uintptr_t)g,
                                     (ls_void*)(uintptr_t)l, 16, 0, 0);
}

__device__ __forceinline__ unsigned short f2bf(float x) {
    union { float f; unsigned u; } c; c.f = x;
    unsigned r = c.u + 0x7fffu + ((c.u >> 16) & 1u);  // RNE, no NaN inputs
    return (unsigned short)(r >> 16);
}

#define WAITVM(n) do { \
    asm volatile("s_waitcnt vmcnt(" #n ")" ::: "memory"); \
    __builtin_amdgcn_sched_barrier(0); \
} while (0)

#define WAITLGKM0 do { \
    asm volatile("s_waitcnt lgkmcnt(0)" ::: "memory"); \
    __builtin_amdgcn_sched_barrier(0); \
} while (0)

// ---------------- prep: centroids + normalization -> bf16 ----------------
__global__ __launch_bounds__(256) void prep_kernel(const float* __restrict__ emb,
                                                   unsigned short* __restrict__ tn,
                                                   unsigned short* __restrict__ cn,
                                                   float* __restrict__ zbuf)
{
    if (blockIdx.x == 0) {
        #pragma unroll
        for (int i = 0; i < 16; ++i) zbuf[threadIdx.x + 256 * i] = 0.0f;   // total+pos
    }

    const int w = threadIdx.x >> 6;
    const int l = threadIdx.x & 63;
    const int task = blockIdx.x * 4 + w;

    float4 v;
    if (task < M_ROWS) {
        const int m = task >> 4;
        const int t = task & 15;
        const size_t grow = (size_t)m * UU + HALF_U + t;
        v = *(const float4*)(emb + grow * DD + 4 * l);
    } else {
        const int n = task - M_ROWS;
        float ax = 0.f, ay = 0.f, az = 0.f, aw = 0.f;
        const float* base = emb + (size_t)n * UU * DD + 4 * l;
        #pragma unroll
        for (int j = 0; j < HALF_U; ++j) {
            float4 e = *(const float4*)(base + j * DD);
            ax += e.x; ay += e.y; az += e.z; aw += e.w;
        }
        const float inv = 1.0f / 16.0f;
        v = make_float4(ax * inv, ay * inv, az * inv, aw * inv);
    }
    float ss = v.x * v.x + v.y * v.y + v.z * v.z + v.w * v.w;
    #pragma unroll
    for (int d = 1; d < 64; d <<= 1) ss += __shfl_xor(ss, d);
    const float sc = 1.0f / fmaxf(sqrtf(ss), 1e-8f);

    ushort4 o;
    o.x = f2bf(v.x * sc); o.y = f2bf(v.y * sc);
    o.z = f2bf(v.z * sc); o.w = f2bf(v.w * sc);
    unsigned short* dst = (task < M_ROWS)
        ? (tn + (size_t)task * DD + 4 * l)
        : (cn + (size_t)(task - M_ROWS) * DD + 4 * l);
    *(ushort4*)dst = o;
}

// ---------------- persistent fused GEMM, deep counted-vmcnt pipeline ------
// 256 blocks (1/CU), 512 thr (8 waves, 4M x 2N, per-wave 64x64). Per block:
// fixed bm (256 rows), 8 tiles bn0..bn0+7 (128 cols each) as ONE 32-step
// chained kt-pipeline. LDS: 9 unit-slots x 16 KiB (unit = A-half/A-half/B of
// a j-step, 48 KiB/step -> 3 steps resident). Prefetch depth 2 j-steps:
// issue j+2 during j; boundary waits vmcnt(6) (drains only j+1, issued a
// full step earlier; >=6 loads always in flight; never drain0 in main loop).
// XOR swizzle both sides; setprio around MFMA; lgkmcnt(0)+sched_barrier.
__global__ __launch_bounds__(512, 2) void gemm_kernel(const unsigned short* __restrict__ tnb,
                                                      const unsigned short* __restrict__ cnb,
                                                      const float* __restrict__ alphaP,
                                                      const float* __restrict__ betaP,
                                                      float* __restrict__ total,
                                                      float* __restrict__ pos)
{
    __shared__ __align__(16) char S[9][16384];   // 144 KiB
    __shared__ float csum[BN];

    const int tid = threadIdx.x;
    const int l = tid & 63;
    const int w = tid >> 6;            // 0..7
    const int wr = w >> 1, wc = w & 1; // 4M x 2N; per-wave out 64x64
    const int r16 = l & 15, hi = l >> 4;

    const float alpha = *alphaP;
    const float beta  = *betaP;

    // XCD-local mapping: 32 blocks/XCD cover bm in [xcd*16, xcd*16+16),
    // 2 blocks per bm (bn0 = 0 or 8). A slice 2 MiB + B 1 MiB < 4 MiB L2.
    const int c = blockIdx.x;          // 0..255
    const int xcd = c & 7, slot = c >> 3;
    const int bm = xcd * 16 + (slot >> 1);   // 0..127
    const int bn0 = (slot & 1) * 8;          // 0 or 8

    const char* gA  = (const char*)tnb + (size_t)bm * BM * 512;  // row stride 512B
    const char* gBb = (const char*)cnb;

    // stage unit u (0:A rows 0-127, 1:A rows 128-255, 2:B 128 rows) of step jj
    auto stage_unit = [&](int jj, int u, int ss) {
        const int kt = jj & 3;
        char* dst = S[ss];
        const char* g = (u < 2) ? gA : gBb;
        const int rbase = (u < 2) ? u * 128 : (bn0 + (jj >> 2)) * 128;
        #pragma unroll
        for (int i = 0; i < 2; ++i) {
            const int off = i * 8192 + tid * 16;       // linear LDS byte offset
            const int row = off >> 7;                  // 0..127
            const int sc  = ((off >> 4) & 7) ^ (row & 7);
            gld16(g + (size_t)(rbase + row) * 512 + kt * 128 + sc * 16, dst + off);
        }
    };

    f32x4 acc[4][4] = {};

    // prologue: j0 -> slots 0,1,2 ; j1 -> slots 3,4,5 (12 loads/thread)
    #pragma unroll
    for (int u = 0; u < 3; ++u) stage_unit(0, u, u);
    #pragma unroll
    for (int u = 0; u < 3; ++u) stage_unit(1, u, 3 + u);
    WAITVM(6);                                    // j0 landed, j1 in flight
    __builtin_amdgcn_s_barrier();

    int s0 = 0;                                   // slot base for j (cycles 0,3,6)
    for (int j = 0; j < NSTEP; ++j) {
        const int s2 = (s0 >= 3) ? s0 - 3 : s0 + 6;    // slot base for j+2
        const char* As = S[s0 + (wr >> 1)];            // this wave's A-half
        const char* Bs = S[s0 + 2];
        const int lrA = (wr & 1) * 64;                 // wave's local row base in half
        const int c16k0 = hi ^ (r16 & 7);              // swizzled granule, kk=0
        const int c16k1 = (4 + hi) ^ (r16 & 7);        // kk=1
        short8 b[4][2];

        // ---- phase 0: mi {0,1} ----
        {
            #pragma unroll
            for (int ni = 0; ni < 4; ++ni) {
                const int row = wc * 64 + ni * 16 + r16;
                b[ni][0] = *(const short8*)(Bs + row * 128 + c16k0 * 16);
                b[ni][1] = *(const short8*)(Bs + row * 128 + c16k1 * 16);
            }
            short8 a[2][2];
            #pragma unroll
            for (int m2 = 0; m2 < 2; ++m2) {
                const int row = lrA + m2 * 16 + r16;
                a[m2][0] = *(const short8*)(As + row * 128 + c16k0 * 16);
                a[m2][1] = *(const short8*)(As + row * 128 + c16k1 * 16);
            }
            if (j < NSTEP - 2) { stage_unit(j + 2, 0, s2); stage_unit(j + 2, 1, s2 + 1); }
            __builtin_amdgcn_s_barrier();
            WAITLGKM0;
            __builtin_amdgcn_s_setprio(1);
            #pragma unroll
            for (int kk = 0; kk < 2; ++kk)
                #pragma unroll
                for (int m2 = 0; m2 < 2; ++m2)
                    #pragma unroll
                    for (int ni = 0; ni < 4; ++ni)
                        acc[m2][ni] = __builtin_amdgcn_mfma_f32_16x16x32_bf16(
                            a[m2][kk], b[ni][kk], acc[m2][ni], 0, 0, 0);
            __builtin_amdgcn_s_setprio(0);
            __builtin_amdgcn_s_barrier();
        }

        // ---- phase 1: mi {2,3} ----
        {
            short8 a[2][2];
            #pragma unroll
            for (int m2 = 0; m2 < 2; ++m2) {
                const int row = lrA + (2 + m2) * 16 + r16;
                a[m2][0] = *(const short8*)(As + row * 128 + c16k0 * 16);
                a[m2][1] = *(const short8*)(As + row * 128 + c16k1 * 16);
            }
            if (j < NSTEP - 2) stage_unit(j + 2, 2, s2 + 2);
            __builtin_amdgcn_s_barrier();
            WAITLGKM0;
            __builtin_amdgcn_s_setprio(1);
            #pragma unroll
            for (int kk = 0; kk < 2; ++kk)
                #pragma unroll
                for (int m2 = 0; m2 < 2; ++m2)
                    #pragma unroll
                    for (int ni = 0; ni < 4; ++ni)
                        acc[2 + m2][ni] = __builtin_amdgcn_mfma_f32_16x16x32_bf16(
                            a[m2][kk], b[ni][kk], acc[2 + m2][ni], 0, 0, 0);
            __builtin_amdgcn_s_setprio(0);
            __builtin_amdgcn_s_barrier();
        }

        // ---- per-tile epilogue every 4th step (staging stays in flight) ----
        if ((j & 3) == 3) {
            const int bn = bn0 + (j >> 2);
            const bool diag = ((bm >> 3) == bn);
            if (tid < BN) csum[tid] = 0.0f;
            __builtin_amdgcn_s_barrier();
            #pragma unroll
            for (int ni = 0; ni < 4; ++ni) {
                const int colg = bn * BN + wc * 64 + ni * 16 + r16;  // col = lane&15
                float cs = 0.f;
                #pragma unroll
                for (int mi = 0; mi < 4; ++mi) {
                    const int rowbase = bm * BM + wr * 64 + mi * 16 + hi * 4;
                    #pragma unroll
                    for (int r = 0; r < 4; ++r) {
                        const float e = __expf(alpha * acc[mi][ni][r] + beta);
                        cs += e;
                        if (diag && ((rowbase + r) >> 4) == colg)    // positive pair
                            atomicAdd(pos + colg, e);
                    }
                    acc[mi][ni] = (f32x4){0.f, 0.f, 0.f, 0.f};       // re-zero
                }
                cs += __shfl_xor(cs, 16);
                cs += __shfl_xor(cs, 32);
                if (hi == 0) atomicAdd(&csum[wc * 64 + ni * 16 + r16], cs);
            }
            __builtin_amdgcn_s_barrier();
            if (tid < BN) atomicAdd(total + bn * BN + tid, csum[tid]);
        }

        // ---- boundary: counted wait, never drain0 in steady state ----
        if (j < NSTEP - 1) {
            if (j < NSTEP - 2) { WAITVM(6); }   // drains j+1 only (1 step old)
            else               { WAITVM(0); }   // tail: j31's units (1 step old)
            __builtin_amdgcn_s_barrier();
        }
        s0 = (s0 >= 6) ? 0 : s0 + 3;
    }
}

// ---------------- finalize: loss = mean(log(tot-pos) - log(pos)) ----------
__global__ __launch_bounds__(256) void finalize_kernel(const float* __restrict__ total,
                                                       const float* __restrict__ pos,
                                                       float* __restrict__ out)
{
    const int tid = threadIdx.x;
    float s = 0.f;
    for (int i = tid; i < N_SPK; i += 256) {
        const float p = pos[i];
        const float t = total[i];
        s += logf(t - p) - logf(p);
    }
    #pragma unroll
    for (int d = 1; d < 64; d <<= 1) s += __shfl_xor(s, d);
    __shared__ float wsum[4];
    if ((tid & 63) == 0) wsum[tid >> 6] = s;
    __syncthreads();
    if (tid == 0) out[0] = (wsum[0] + wsum[1] + wsum[2] + wsum[3]) * (1.0f / (float)N_SPK);
}

extern "C" void kernel_launch(void* const* d_in, const int* in_sizes, int n_in,
                              void* d_out, int out_size, void* d_ws, size_t ws_size,
                              hipStream_t stream)
{
    const float* emb    = (const float*)d_in[0];
    const float* alphaP = (const float*)d_in[2];
    const float* betaP  = (const float*)d_in[3];
    float* out = (float*)d_out;

    char* ws = (char*)d_ws;
    unsigned short* tn = (unsigned short*)ws;                       // 16 MiB
    unsigned short* cn = (unsigned short*)(ws + 16777216);          // 1 MiB
    float* total       = (float*)(ws + 16777216 + 1048576);         // 2048 f32
    float* pos         = total + N_SPK;                             // 2048 f32

    hipLaunchKernelGGL(prep_kernel, dim3((M_ROWS + N_SPK) / 4), dim3(256), 0, stream,
                       emb, tn, cn, total /* zeroes total+pos (4096 f32) */);
    hipLaunchKernelGGL(gemm_kernel, dim3(256), dim3(512), 0, stream,
                       tn, cn, alphaP, betaP, total, pos);
    hipLaunchKernelGGL(finalize_kernel, dim3(1), dim3(256), 0, stream,
                       total, pos, out);
}

// Round 6
// 153.675 us; speedup vs baseline: 1.0715x; 1.0715x over previous
//
#include <hip/hip_runtime.h>
#include <hip/hip_bf16.h>
#include <stdint.h>

#define N_SPK 2048
#define UU 32
#define DD 256
#define HALF_U 16
#define M_ROWS (N_SPK * HALF_U)   // 32768 test rows

#define BM 128
#define BN 128
#define BK 64

typedef __attribute__((ext_vector_type(8))) short short8;   // 8 bf16 = 4 VGPRs
typedef __attribute__((ext_vector_type(4))) float f32x4;

typedef const __attribute__((address_space(1))) void ga_void;
typedef __attribute__((address_space(3))) void ls_void;

__device__ __forceinline__ void gld16(const void* g, void* l) {
    __builtin_amdgcn_global_load_lds((ga_void*)(uintptr_t)g,
                                     (ls_void*)(uintptr_t)l, 16, 0, 0);
}

__device__ __forceinline__ unsigned short f2bf(float x) {
    union { float f; unsigned u; } c; c.f = x;
    unsigned r = c.u + 0x7fffu + ((c.u >> 16) & 1u);  // RNE, no NaN inputs
    return (unsigned short)(r >> 16);
}

// ---------------- prep: centroids + normalization -> bf16 ----------------
__global__ __launch_bounds__(256) void prep_kernel(const float* __restrict__ emb,
                                                   unsigned short* __restrict__ tn,
                                                   unsigned short* __restrict__ cn,
                                                   float* __restrict__ zbuf)
{
    if (blockIdx.x == 0) {
        #pragma unroll
        for (int i = 0; i < 16; ++i) zbuf[threadIdx.x + 256 * i] = 0.0f;   // total+pos
    }

    const int w = threadIdx.x >> 6;
    const int l = threadIdx.x & 63;
    const int task = blockIdx.x * 4 + w;

    float4 v;
    if (task < M_ROWS) {
        const int m = task >> 4;
        const int t = task & 15;
        const size_t grow = (size_t)m * UU + HALF_U + t;
        v = *(const float4*)(emb + grow * DD + 4 * l);
    } else {
        const int n = task - M_ROWS;
        float ax = 0.f, ay = 0.f, az = 0.f, aw = 0.f;
        const float* base = emb + (size_t)n * UU * DD + 4 * l;
        #pragma unroll
        for (int j = 0; j < HALF_U; ++j) {
            float4 e = *(const float4*)(base + j * DD);
            ax += e.x; ay += e.y; az += e.z; aw += e.w;
        }
        const float inv = 1.0f / 16.0f;
        v = make_float4(ax * inv, ay * inv, az * inv, aw * inv);
    }
    float ss = v.x * v.x + v.y * v.y + v.z * v.z + v.w * v.w;
    #pragma unroll
    for (int d = 1; d < 64; d <<= 1) ss += __shfl_xor(ss, d);
    const float sc = 1.0f / fmaxf(sqrtf(ss), 1e-8f);

    ushort4 o;
    o.x = f2bf(v.x * sc); o.y = f2bf(v.y * sc);
    o.z = f2bf(v.z * sc); o.w = f2bf(v.w * sc);
    unsigned short* dst = (task < M_ROWS)
        ? (tn + (size_t)task * DD + 4 * l)
        : (cn + (size_t)(task - M_ROWS) * DD + 4 * l);
    *(ushort4*)dst = o;
}

// ---------------- fused GEMM: m97 structure, 3 blocks/CU ------------------
// 128x128 tile, BK=64, 256 thr (4 waves 2x2, per-wave 64x64), single-buffer
// 32 KiB LDS, stage -> sync -> MFMA -> sync. Cross-BLOCK wave overlap (3
// blocks/CU) hides the barrier drains (m97/m114 mechanism). XOR swizzle on
// both sides; no setprio (m190: null on this structure).
__global__ __launch_bounds__(256, 3) void gemm_kernel(const unsigned short* __restrict__ tnb,
                                                      const unsigned short* __restrict__ cnb,
                                                      const float* __restrict__ alphaP,
                                                      const float* __restrict__ betaP,
                                                      float* __restrict__ total,
                                                      float* __restrict__ pos)
{
    __shared__ __align__(16) char As[BM * BK * 2];   // 16 KiB
    __shared__ __align__(16) char Bs[BN * BK * 2];   // 16 KiB
    __shared__ float csum[BN];

    const int tid = threadIdx.x;
    const int l = tid & 63;
    const int w = tid >> 6;            // 0..3
    const int wr = w >> 1, wc = w & 1; // 2M x 2N; per-wave out 64x64
    const int r16 = l & 15, hi = l >> 4;

    // XCD swizzle: grid 4096 = 8 XCDs x 512 contiguous tiles.
    // Per XCD: bm in [xcd*32, xcd*32+32) x all 16 bn -> A 2 MiB + B 1 MiB in L2.
    const int bid = blockIdx.x;
    const int tile = (bid & 7) * 512 + (bid >> 3);
    const int bm = tile >> 4;          // 0..255
    const int bn = tile & 15;          // 0..15

    const char* gA = (const char*)tnb + (size_t)bm * BM * 512;   // row stride 512 B
    const char* gB = (const char*)cnb + (size_t)bn * BN * 512;

    f32x4 acc[4][4] = {};

    for (int kt = 0; kt < 4; ++kt) {
        // ---- stage 128x64 of A and B (8 gld16/thread) ----
        #pragma unroll
        for (int i = 0; i < 4; ++i) {
            const int off = i * 4096 + tid * 16;       // linear LDS byte offset
            const int row = off >> 7;                  // 0..127
            const int sc  = ((off >> 4) & 7) ^ (row & 7);
            const int goff = row * 512 + kt * 128 + sc * 16;
            gld16(gA + goff, As + off);
            gld16(gB + goff, Bs + off);
        }
        __syncthreads();               // compiler inserts vmcnt(0): tiles landed

        // ---- 32 MFMA from LDS (compiler schedules fine-grained lgkmcnt) ----
        #pragma unroll
        for (int kk = 0; kk < 2; ++kk) {
            short8 a[4], b[4];
            #pragma unroll
            for (int ni = 0; ni < 4; ++ni) {
                const int row = wc * 64 + ni * 16 + r16;
                const int c16 = (kk * 4 + hi) ^ (row & 7);
                b[ni] = *(const short8*)(Bs + row * 128 + c16 * 16);
            }
            #pragma unroll
            for (int mi = 0; mi < 4; ++mi) {
                const int row = wr * 64 + mi * 16 + r16;
                const int c16 = (kk * 4 + hi) ^ (row & 7);
                a[mi] = *(const short8*)(As + row * 128 + c16 * 16);
            }
            #pragma unroll
            for (int mi = 0; mi < 4; ++mi)
                #pragma unroll
                for (int ni = 0; ni < 4; ++ni)
                    acc[mi][ni] = __builtin_amdgcn_mfma_f32_16x16x32_bf16(
                        a[mi], b[ni], acc[mi][ni], 0, 0, 0);
        }
        __syncthreads();               // all reads done before next overwrite
    }

    // ---- epilogue: exp, column sums, diagonal ----
    const float alpha = *alphaP;
    const float beta  = *betaP;
    const bool diag = ((bm >> 4) == bn);   // this tile contains positive pairs

    if (tid < BN) csum[tid] = 0.0f;
    __syncthreads();

    #pragma unroll
    for (int ni = 0; ni < 4; ++ni) {
        const int colg = bn * BN + wc * 64 + ni * 16 + r16;   // C/D: col = lane&15
        float cs = 0.f;
        #pragma unroll
        for (int mi = 0; mi < 4; ++mi) {
            const int rowbase = bm * BM + wr * 64 + mi * 16 + hi * 4;  // row=(l>>4)*4+r
            #pragma unroll
            for (int r = 0; r < 4; ++r) {
                const float e = __expf(alpha * acc[mi][ni][r] + beta);
                cs += e;
                if (diag && ((rowbase + r) >> 4) == colg)     // positive pair
                    atomicAdd(pos + colg, e);
            }
        }
        cs += __shfl_xor(cs, 16);
        cs += __shfl_xor(cs, 32);
        if (hi == 0) atomicAdd(&csum[wc * 64 + ni * 16 + r16], cs);
    }
    __syncthreads();
    if (tid < BN) atomicAdd(total + bn * BN + tid, csum[tid]);
}

// ---------------- finalize: loss = mean(log(tot-pos) - log(pos)) ----------
__global__ __launch_bounds__(256) void finalize_kernel(const float* __restrict__ total,
                                                       const float* __restrict__ pos,
                                                       float* __restrict__ out)
{
    const int tid = threadIdx.x;
    float s = 0.f;
    for (int i = tid; i < N_SPK; i += 256) {
        const float p = pos[i];
        const float t = total[i];
        s += logf(t - p) - logf(p);
    }
    #pragma unroll
    for (int d = 1; d < 64; d <<= 1) s += __shfl_xor(s, d);
    __shared__ float wsum[4];
    if ((tid & 63) == 0) wsum[tid >> 6] = s;
    __syncthreads();
    if (tid == 0) out[0] = (wsum[0] + wsum[1] + wsum[2] + wsum[3]) * (1.0f / (float)N_SPK);
}

extern "C" void kernel_launch(void* const* d_in, const int* in_sizes, int n_in,
                              void* d_out, int out_size, void* d_ws, size_t ws_size,
                              hipStream_t stream)
{
    const float* emb    = (const float*)d_in[0];
    const float* alphaP = (const float*)d_in[2];
    const float* betaP  = (const float*)d_in[3];
    float* out = (float*)d_out;

    char* ws = (char*)d_ws;
    unsigned short* tn = (unsigned short*)ws;                       // 16 MiB
    unsigned short* cn = (unsigned short*)(ws + 16777216);          // 1 MiB
    float* total       = (float*)(ws + 16777216 + 1048576);         // 2048 f32
    float* pos         = total + N_SPK;                             // 2048 f32

    hipLaunchKernelGGL(prep_kernel, dim3((M_ROWS + N_SPK) / 4), dim3(256), 0, stream,
                       emb, tn, cn, total /* zeroes total+pos (4096 f32) */);
    hipLaunchKernelGGL(gemm_kernel, dim3(M_ROWS / BM * (N_SPK / BN)), dim3(256), 0, stream,
                       tn, cn, alphaP, betaP, total, pos);
    hipLaunchKernelGGL(finalize_kernel, dim3(1), dim3(256), 0, stream,
                       total, pos, out);
}